// Round 1
// baseline (540.652 us; speedup 1.0000x reference)
//
#include <hip/hip_runtime.h>

// LeakySNN fused kernel: out[b] = b2 + sum_h spksum(x1[b,h]) * W2[h]
//   x1[b,h] = dot(x[b,:], W1[h,:]) + b1[h]
//   25-step LIF scan per (b,h), all in registers.
// Fully fused: x1 / spk_sum (128 MB each) never touch memory.

#define NI 256
#define NH 1024
#define NSTEPS 25
#define BT 64          // batch tile
#define HT 64          // hidden tile
#define BK 64          // k tile
#define LROW (BK + 4)  // 68 floats: rows stay 16B-aligned for b128 LDS ops

__global__ __launch_bounds__(256) void snn_init(float* __restrict__ out,
                                                const float* __restrict__ b2, int B) {
    int i = blockIdx.x * 256 + threadIdx.x;
    if (i < B) out[i] = b2[0];
}

__global__ __launch_bounds__(256, 4) void snn_main(
    const float* __restrict__ x, const float* __restrict__ W1,
    const float* __restrict__ b1, const float* __restrict__ W2,
    const float* __restrict__ betap, const float* __restrict__ thr,
    float* __restrict__ out)
{
    __shared__ float xs[BT][LROW];
    __shared__ float ws[HT][LROW];
    __shared__ float red[BT][17];

    const int tid = threadIdx.x;
    const int tx = tid & 15;    // h group: cols tx*4 .. tx*4+3
    const int ty = tid >> 4;    // b group: rows ty*4 .. ty*4+3
    const int b0 = blockIdx.x * BT;
    const int h0 = blockIdx.y * HT;

    float beta = betap[0];
    beta = beta < 0.f ? 0.f : (beta > 1.f ? 1.f : beta);

    float acc[4][4];
#pragma unroll
    for (int i = 0; i < 4; i++)
#pragma unroll
        for (int j = 0; j < 4; j++) acc[i][j] = 0.f;

    // staging map: thread (sr, sc) loads float4 at rows sr+16*i, k-chunk sc
    const int sc = tid & 15;   // 16B chunk within k-tile
    const int sr = tid >> 4;   // base row

    for (int k0 = 0; k0 < NI; k0 += BK) {
        __syncthreads();  // previous tile fully consumed before overwrite
#pragma unroll
        for (int i = 0; i < 4; i++) {
            int row = sr + 16 * i;
            float4 vx = *(const float4*)&x[(size_t)(b0 + row) * NI + k0 + 4 * sc];
            *(float4*)&xs[row][4 * sc] = vx;
            float4 vw = *(const float4*)&W1[(size_t)(h0 + row) * NI + k0 + 4 * sc];
            *(float4*)&ws[row][4 * sc] = vw;
        }
        __syncthreads();
#pragma unroll
        for (int k = 0; k < BK; k += 4) {
            float4 xa[4], wb[4];
#pragma unroll
            for (int i = 0; i < 4; i++) xa[i] = *(const float4*)&xs[ty * 4 + i][k];
#pragma unroll
            for (int j = 0; j < 4; j++) wb[j] = *(const float4*)&ws[tx * 4 + j][k];
#pragma unroll
            for (int i = 0; i < 4; i++)
#pragma unroll
                for (int j = 0; j < 4; j++) {
                    acc[i][j] = fmaf(xa[i].x, wb[j].x, acc[i][j]);
                    acc[i][j] = fmaf(xa[i].y, wb[j].y, acc[i][j]);
                    acc[i][j] = fmaf(xa[i].z, wb[j].z, acc[i][j]);
                    acc[i][j] = fmaf(xa[i].w, wb[j].w, acc[i][j]);
                }
        }
    }

    // ---- LIF scan, fully in registers ----
    // reference step: reset = spike(mem - thr); mem' = beta*mem + x1 - reset*thr;
    //                 spk = spike(mem' - thr)
    // identity: reset_t == spk_{t-1}; reset_0 = spike(0 - thr).
    float part[4] = {0.f, 0.f, 0.f, 0.f};
#pragma unroll
    for (int j = 0; j < 4; j++) {
        const int h = h0 + tx * 4 + j;
        const float th = thr[h];
        const float nth = -th;
        const float w2 = W2[h];
        const float bj = b1[h];
#pragma unroll
        for (int i = 0; i < 4; i++) {
            const float x1 = acc[i][j] + bj;
            float mem = 0.f;
            float spk = (0.f - th > 0.f) ? 1.f : 0.f;  // reset_0
            float ss = 0.f;
#pragma unroll
            for (int t = 0; t < NSTEPS; t++) {
                mem = fmaf(spk, nth, fmaf(beta, mem, x1));  // exact: t - spk*th
                spk = (mem - th > 0.f) ? 1.f : 0.f;
                ss += spk;
            }
            part[i] = fmaf(ss, w2, part[i]);
        }
    }

    // ---- reduce over the 16 h-groups in the block, one atomic per b ----
#pragma unroll
    for (int i = 0; i < 4; i++) red[ty * 4 + i][tx] = part[i];
    __syncthreads();
    if (tid < BT) {
        float s = 0.f;
#pragma unroll
        for (int t = 0; t < 16; t++) s += red[tid][t];
        atomicAdd(&out[b0 + tid], s);
    }
}

extern "C" void kernel_launch(void* const* d_in, const int* in_sizes, int n_in,
                              void* d_out, int out_size, void* d_ws, size_t ws_size,
                              hipStream_t stream) {
    const float* x    = (const float*)d_in[0];
    const float* W1   = (const float*)d_in[1];
    const float* b1   = (const float*)d_in[2];
    const float* W2   = (const float*)d_in[3];
    const float* b2   = (const float*)d_in[4];
    const float* beta = (const float*)d_in[5];
    const float* thr  = (const float*)d_in[6];
    float* out = (float*)d_out;

    const int B = in_sizes[0] / NI;  // 32768

    snn_init<<<(B + 255) / 256, 256, 0, stream>>>(out, b2, B);

    dim3 grid(B / BT, NH / HT);
    snn_main<<<grid, 256, 0, stream>>>(x, W1, b1, W2, beta, thr, out);
}

// Round 2
// 426.214 us; speedup vs baseline: 1.2685x; 1.2685x over previous
//
#include <hip/hip_runtime.h>

// LeakySNN fused kernel: out[b] = b2 + sum_h spksum(x1[b,h]) * W2[h]
//   x1[b,h] = dot(x[b,:], W1[h,:]) + b1[h];  25-step LIF scan in registers.
// R1: tile remap h=tx+16j, b=ty+16i -> LDS lane stride = 1 row (68 words ==
//     4 mod 32) so B-fragment reads are 2-way (free) instead of 8-way.

#define NI 256
#define NH 1024
#define NSTEPS 25
#define BT 64          // batch tile
#define HT 64          // hidden tile
#define BK 64          // k tile
#define LROW (BK + 4)  // 68 floats: rows 16B-aligned, stride 4 mod 32 banks

__global__ __launch_bounds__(256) void snn_init(float* __restrict__ out,
                                                const float* __restrict__ b2, int B) {
    int i = blockIdx.x * 256 + threadIdx.x;
    if (i < B) out[i] = b2[0];
}

__global__ __launch_bounds__(256, 4) void snn_main(
    const float* __restrict__ x, const float* __restrict__ W1,
    const float* __restrict__ b1, const float* __restrict__ W2,
    const float* __restrict__ betap, const float* __restrict__ thr,
    float* __restrict__ out)
{
    __shared__ float xs[BT][LROW];
    __shared__ float ws[HT][LROW];
    __shared__ float red[BT][17];

    const int tid = threadIdx.x;
    const int tx = tid & 15;    // h lane: cols tx + 16*j
    const int ty = tid >> 4;    // b lane: rows ty + 16*i
    const int b0 = blockIdx.x * BT;
    const int h0 = blockIdx.y * HT;

    float beta = betap[0];
    beta = beta < 0.f ? 0.f : (beta > 1.f ? 1.f : beta);

    float acc[4][4];
#pragma unroll
    for (int i = 0; i < 4; i++)
#pragma unroll
        for (int j = 0; j < 4; j++) acc[i][j] = 0.f;

    // staging map: thread (sr, sc) loads float4 at rows sr+16*i, k-chunk sc
    const int sc = tid & 15;   // 16B chunk within k-tile (fastest -> coalesced)
    const int sr = tid >> 4;   // base row

    for (int k0 = 0; k0 < NI; k0 += BK) {
        __syncthreads();  // previous tile fully consumed before overwrite
#pragma unroll
        for (int i = 0; i < 4; i++) {
            int row = sr + 16 * i;
            float4 vx = *(const float4*)&x[(size_t)(b0 + row) * NI + k0 + 4 * sc];
            *(float4*)&xs[row][4 * sc] = vx;
            float4 vw = *(const float4*)&W1[(size_t)(h0 + row) * NI + k0 + 4 * sc];
            *(float4*)&ws[row][4 * sc] = vw;
        }
        __syncthreads();
#pragma unroll
        for (int k = 0; k < BK; k += 4) {
            float4 xa[4], wb[4];
#pragma unroll
            for (int i = 0; i < 4; i++) xa[i] = *(const float4*)&xs[ty + 16 * i][k];
#pragma unroll
            for (int j = 0; j < 4; j++) wb[j] = *(const float4*)&ws[tx + 16 * j][k];
#pragma unroll
            for (int i = 0; i < 4; i++)
#pragma unroll
                for (int j = 0; j < 4; j++) {
                    acc[i][j] = fmaf(xa[i].x, wb[j].x, acc[i][j]);
                    acc[i][j] = fmaf(xa[i].y, wb[j].y, acc[i][j]);
                    acc[i][j] = fmaf(xa[i].z, wb[j].z, acc[i][j]);
                    acc[i][j] = fmaf(xa[i].w, wb[j].w, acc[i][j]);
                }
        }
    }

    // ---- LIF scan, fully in registers ----
    // reset_t == spk_{t-1}; reset_0 = spike(0 - thr). 5 VALU ops/step:
    // 2 fma (mem), cmp, cndmask (spk), add (ss).
    float part[4] = {0.f, 0.f, 0.f, 0.f};
#pragma unroll
    for (int j = 0; j < 4; j++) {
        const int h = h0 + tx + 16 * j;
        const float th = thr[h];
        const float nth = -th;
        const float w2 = W2[h];
        const float bj = b1[h];
#pragma unroll
        for (int i = 0; i < 4; i++) {
            const float x1 = acc[i][j] + bj;
            float mem = 0.f;
            float spk = (0.f > th) ? 1.f : 0.f;  // reset_0 = spike(-thr)
            float ss = 0.f;
#pragma unroll
            for (int t = 0; t < NSTEPS; t++) {
                mem = fmaf(spk, nth, fmaf(beta, mem, x1));  // beta*mem + x1 - spk*th
                spk = (mem > th) ? 1.f : 0.f;               // a-b>0 <=> a>b
                ss += spk;
            }
            part[i] = fmaf(ss, w2, part[i]);
        }
    }

    // ---- reduce over the 16 h-lanes in the block, one atomic per b ----
#pragma unroll
    for (int i = 0; i < 4; i++) red[ty + 16 * i][tx] = part[i];
    __syncthreads();
    if (tid < BT) {
        float s = 0.f;
#pragma unroll
        for (int t = 0; t < 16; t++) s += red[tid][t];
        atomicAdd(&out[b0 + tid], s);
    }
}

extern "C" void kernel_launch(void* const* d_in, const int* in_sizes, int n_in,
                              void* d_out, int out_size, void* d_ws, size_t ws_size,
                              hipStream_t stream) {
    const float* x    = (const float*)d_in[0];
    const float* W1   = (const float*)d_in[1];
    const float* b1   = (const float*)d_in[2];
    const float* W2   = (const float*)d_in[3];
    const float* b2   = (const float*)d_in[4];
    const float* beta = (const float*)d_in[5];
    const float* thr  = (const float*)d_in[6];
    float* out = (float*)d_out;

    const int B = in_sizes[0] / NI;  // 32768

    snn_init<<<(B + 255) / 256, 256, 0, stream>>>(out, b2, B);

    dim3 grid(B / BT, NH / HT);
    snn_main<<<grid, 256, 0, stream>>>(x, W1, b1, W2, beta, thr, out);
}

// Round 3
// 373.488 us; speedup vs baseline: 1.4476x; 1.1412x over previous
//
#include <hip/hip_runtime.h>

// LeakySNN fused: out[b] = b2 + sum_h spksum(x1[b,h]) * W2[h]
//   x1 = x @ W1^T + b1 (fp32 vector GEMM, no fp32 MFMA on CDNA4), then
//   25-step LIF scan in registers, then W2 reduction. x1/spk_sum never hit HBM.
// R2: 8x8 register tile (1 B/FMA LDS intensity, was 2), global_load_lds
//     16B staging with XOR-swizzled unpadded LDS layout, wave = 8x8 lanes
//     so fragment reads are 8 unique rows x 8-way broadcast, bank-balanced.

#define NI 256
#define NH 1024
#define NSTEPS 25
#define BT 128         // batch tile
#define HT 128         // hidden tile
#define BK 32          // k tile (8 float4 chunks)
#define NTILES (NI / BK)

__device__ __forceinline__ void async_load16(const float* g, float* l) {
    __builtin_amdgcn_global_load_lds(
        (const __attribute__((address_space(1))) void*)g,
        (__attribute__((address_space(3))) void*)l, 16, 0, 0);
}

__global__ __launch_bounds__(256) void snn_init(float* __restrict__ out,
                                                const float* __restrict__ b2, int B) {
    int i = blockIdx.x * 256 + threadIdx.x;
    if (i < B) out[i] = b2[0];
}

__global__ __launch_bounds__(256, 3) void snn_main(
    const float* __restrict__ x, const float* __restrict__ W1,
    const float* __restrict__ b1, const float* __restrict__ W2,
    const float* __restrict__ betap, const float* __restrict__ thr,
    float* __restrict__ out)
{
    __shared__ float smem[2 * BT * BK];       // xs[128][32] ++ ws[128][32], no pad
    float* xs  = smem;
    float* wsm = smem + BT * BK;

    const int tid  = threadIdx.x;
    const int w    = tid >> 6;                // wave 0..3
    const int lane = tid & 63;
    const int ltx  = lane & 7;                // h sub-lane
    const int lty  = (lane >> 3) & 7;         // b sub-lane
    const int wh   = (w & 1) * 64;            // wave h offset in tile
    const int wb_  = (w >> 1) * 64;           // wave b offset in tile
    const int b0 = blockIdx.x * BT;
    const int h0 = blockIdx.y * HT;

    float beta = betap[0];
    beta = beta < 0.f ? 0.f : (beta > 1.f ? 1.f : beta);

    // ---- staging map: wave w stages tile rows [w*32, w*32+32) ----
    // lane l writes LDS base + 16*l: row = l>>3, phys chunk = l&7.
    // XOR swizzle applied on the GLOBAL side: phys chunk c' holds global
    // k-chunk c'^(row&7)  (coalescing unaffected: same 128B row segment).
    const int srow = lane >> 3;               // 0..7
    const int sc   = (lane & 7) ^ srow;       // global k-chunk this lane fetches

    const float* xg = x  + (size_t)(b0 + w * 32 + srow) * NI + 4 * sc;
    const float* wg = W1 + (size_t)(h0 + w * 32 + srow) * NI + 4 * sc;
    float* xl = xs  + (w * 32) * BK;          // wave-uniform LDS dests
    float* wl = wsm + (w * 32) * BK;

    float acc[8][8];
#pragma unroll
    for (int i = 0; i < 8; i++)
#pragma unroll
        for (int j = 0; j < 8; j++) acc[i][j] = 0.f;

    // read bases: thread's h rows = wh + ltx + 8j, b rows = wb_ + lty + 8i.
    // row&7 == ltx (resp. lty), so element (row, k-chunk c) sits at phys
    // chunk c^ltx (wb) / c^lty (xa). Iterating phys chunk q for wb gives
    // logical c = q^ltx; the matching xa phys chunk = q ^ (ltx^lty).
    const float* wbase = wsm + (wh + ltx) * BK;
    const float* xbase = xs + (wb_ + lty) * BK;
    const int sexl = (ltx ^ lty) << 2;        // float-unit XOR offset; 4*(q^e) = (4q)^(4e)

    for (int kt = 0; kt < NTILES; kt++) {
        __syncthreads();                      // previous tile fully consumed
#pragma unroll
        for (int i = 0; i < 4; i++) {
            async_load16(xg + i * 8 * NI, xl + i * 8 * BK);
            async_load16(wg + i * 8 * NI, wl + i * 8 * BK);
        }
        xg += BK; wg += BK;
        __syncthreads();                      // vmcnt(0) drained before barrier

#pragma unroll
        for (int q = 0; q < 8; q++) {
            float4 wbv[8];
#pragma unroll
            for (int j = 0; j < 8; j++)
                wbv[j] = *(const float4*)(wbase + j * 8 * BK + 4 * q);
            const float* xaddr = xbase + ((4 * q) ^ sexl);
#pragma unroll
            for (int i = 0; i < 8; i++) {
                float4 xa = *(const float4*)(xaddr + i * 8 * BK);
#pragma unroll
                for (int j = 0; j < 8; j++) {
                    acc[i][j] = fmaf(xa.x, wbv[j].x, acc[i][j]);
                    acc[i][j] = fmaf(xa.y, wbv[j].y, acc[i][j]);
                    acc[i][j] = fmaf(xa.z, wbv[j].z, acc[i][j]);
                    acc[i][j] = fmaf(xa.w, wbv[j].w, acc[i][j]);
                }
            }
        }
    }

    // ---- LIF scan: reset_t == spk_{t-1}; 5 VALU/step, 8-way ILP ----
    float part[8];
#pragma unroll
    for (int i = 0; i < 8; i++) part[i] = 0.f;

#pragma unroll
    for (int j = 0; j < 8; j++) {
        const int h = h0 + wh + ltx + 8 * j;
        const float th = thr[h];
        const float nth = -th;
        const float w2 = W2[h];
        const float bj = b1[h];
        float mem[8], spk[8], ss[8], x1[8];
#pragma unroll
        for (int i = 0; i < 8; i++) {
            x1[i]  = acc[i][j] + bj;
            mem[i] = 0.f;
            ss[i]  = 0.f;
            spk[i] = (0.f > th) ? 1.f : 0.f;  // reset_0 = spike(-thr)
        }
#pragma unroll 1
        for (int t = 0; t < NSTEPS; t++) {
#pragma unroll
            for (int i = 0; i < 8; i++) {
                mem[i] = fmaf(spk[i], nth, fmaf(beta, mem[i], x1[i]));
                spk[i] = (mem[i] > th) ? 1.f : 0.f;
                ss[i] += spk[i];
            }
        }
#pragma unroll
        for (int i = 0; i < 8; i++) part[i] = fmaf(ss[i], w2, part[i]);
    }

    // ---- block reduction over 16 h-lane groups, one atomic per b ----
    __syncthreads();                          // all waves done reading GEMM LDS
    float (*red)[17] = (float (*)[17])smem;   // 128 x 17 floats, aliases xs
#pragma unroll
    for (int i = 0; i < 8; i++)
        red[wb_ + lty + 8 * i][ltx + 8 * (w & 1)] = part[i];
    __syncthreads();
    if (tid < BT) {
        float s = 0.f;
#pragma unroll
        for (int c = 0; c < 16; c++) s += red[tid][c];
        atomicAdd(&out[b0 + tid], s);
    }
}

extern "C" void kernel_launch(void* const* d_in, const int* in_sizes, int n_in,
                              void* d_out, int out_size, void* d_ws, size_t ws_size,
                              hipStream_t stream) {
    const float* x    = (const float*)d_in[0];
    const float* W1   = (const float*)d_in[1];
    const float* b1   = (const float*)d_in[2];
    const float* W2   = (const float*)d_in[3];
    const float* b2   = (const float*)d_in[4];
    const float* beta = (const float*)d_in[5];
    const float* thr  = (const float*)d_in[6];
    float* out = (float*)d_out;

    const int B = in_sizes[0] / NI;  // 32768

    snn_init<<<(B + 255) / 256, 256, 0, stream>>>(out, b2, B);

    dim3 grid(B / BT, NH / HT);
    snn_main<<<grid, 256, 0, stream>>>(x, W1, b1, W2, beta, thr, out);
}

// Round 4
// 355.645 us; speedup vs baseline: 1.5202x; 1.0502x over previous
//
#include <hip/hip_runtime.h>

// LeakySNN fused: out[b] = b2 + sum_h spksum(x1[b,h]) * W2[h]
//   x1 = x @ W1^T + b1 (fp32 vector GEMM; no fp32 MFMA on CDNA4), then
//   25-step LIF scan in registers, then W2 reduction. x1/spk_sum never hit HBM.
// R3: fix bank conflicts — iterate LOGICAL k-chunk c; per-operand XOR
//     (4c)^(4*ltx) for W-frags, (4c)^(4*lty) for X-frags. Each fragment read
//     now hits 8 distinct bank groups (conflict-free, 8-way broadcast free).

#define NI 256
#define NH 1024
#define NSTEPS 25
#define BT 128         // batch tile
#define HT 128         // hidden tile
#define BK 32          // k tile (8 float4 chunks)
#define NTILES (NI / BK)

__device__ __forceinline__ void async_load16(const float* g, float* l) {
    __builtin_amdgcn_global_load_lds(
        (const __attribute__((address_space(1))) void*)g,
        (__attribute__((address_space(3))) void*)l, 16, 0, 0);
}

__global__ __launch_bounds__(256) void snn_init(float* __restrict__ out,
                                                const float* __restrict__ b2, int B) {
    int i = blockIdx.x * 256 + threadIdx.x;
    if (i < B) out[i] = b2[0];
}

__global__ __launch_bounds__(256, 3) void snn_main(
    const float* __restrict__ x, const float* __restrict__ W1,
    const float* __restrict__ b1, const float* __restrict__ W2,
    const float* __restrict__ betap, const float* __restrict__ thr,
    float* __restrict__ out)
{
    __shared__ float smem[2 * BT * BK];       // xs[128][32] ++ ws[128][32], no pad
    float* xs  = smem;
    float* wsm = smem + BT * BK;

    const int tid  = threadIdx.x;
    const int w    = tid >> 6;                // wave 0..3
    const int lane = tid & 63;
    const int ltx  = lane & 7;                // h sub-lane
    const int lty  = (lane >> 3) & 7;         // b sub-lane
    const int wh   = (w & 1) * 64;            // wave h offset in tile
    const int wb_  = (w >> 1) * 64;           // wave b offset in tile
    const int b0 = blockIdx.x * BT;
    const int h0 = blockIdx.y * HT;

    float beta = betap[0];
    beta = beta < 0.f ? 0.f : (beta > 1.f ? 1.f : beta);

    // ---- staging: wave w stages rows [w*32, w*32+32); lane l writes LDS
    // base+16*l => row=l>>3, phys chunk=l&7. XOR swizzle on the GLOBAL side:
    // phys chunk p of row r holds global k-chunk p^(r&7) (same 128B segment,
    // coalescing unaffected).
    const int srow = lane >> 3;               // 0..7
    const int sc   = (lane & 7) ^ srow;       // global k-chunk this lane fetches

    const float* xg = x  + (size_t)(b0 + w * 32 + srow) * NI + 4 * sc;
    const float* wg = W1 + (size_t)(h0 + w * 32 + srow) * NI + 4 * sc;
    float* xl = xs  + (w * 32) * BK;          // wave-uniform LDS dests
    float* wl = wsm + (w * 32) * BK;

    float acc[8][8];
#pragma unroll
    for (int i = 0; i < 8; i++)
#pragma unroll
        for (int j = 0; j < 8; j++) acc[i][j] = 0.f;

    // read bases: thread's h rows = wh+ltx+8j (row&7==ltx), b rows =
    // wb_+lty+8i (row&7==lty). Element (row, logical chunk c) lives at phys
    // chunk c^(row&7) -> float offset (4c)^(4*(row&7)) within the row.
    const float* wbase = wsm + (wh + ltx) * BK;
    const float* xbase = xs + (wb_ + lty) * BK;
    const int wxor = ltx << 2;                // float-unit XOR for W-frags
    const int xxor = lty << 2;                // float-unit XOR for X-frags

    for (int kt = 0; kt < NTILES; kt++) {
        __syncthreads();                      // previous tile fully consumed
#pragma unroll
        for (int i = 0; i < 4; i++) {
            async_load16(xg + i * 8 * NI, xl + i * 8 * BK);
            async_load16(wg + i * 8 * NI, wl + i * 8 * BK);
        }
        xg += BK; wg += BK;
        __syncthreads();                      // vmcnt(0) drained before barrier

#pragma unroll
        for (int c = 0; c < 8; c++) {         // LOGICAL chunk
            const float* waddr = wbase + ((4 * c) ^ wxor);
            const float* xaddr = xbase + ((4 * c) ^ xxor);
            float4 wbv[8];
#pragma unroll
            for (int j = 0; j < 8; j++)
                wbv[j] = *(const float4*)(waddr + j * 8 * BK);
#pragma unroll
            for (int i = 0; i < 8; i++) {
                float4 xa = *(const float4*)(xaddr + i * 8 * BK);
#pragma unroll
                for (int j = 0; j < 8; j++) {
                    acc[i][j] = fmaf(xa.x, wbv[j].x, acc[i][j]);
                    acc[i][j] = fmaf(xa.y, wbv[j].y, acc[i][j]);
                    acc[i][j] = fmaf(xa.z, wbv[j].z, acc[i][j]);
                    acc[i][j] = fmaf(xa.w, wbv[j].w, acc[i][j]);
                }
            }
        }
    }

    // ---- LIF scan: reset_t == spk_{t-1}; 5 VALU/step, 8-way ILP ----
    float part[8];
#pragma unroll
    for (int i = 0; i < 8; i++) part[i] = 0.f;

#pragma unroll
    for (int j = 0; j < 8; j++) {
        const int h = h0 + wh + ltx + 8 * j;
        const float th = thr[h];
        const float nth = -th;
        const float w2 = W2[h];
        const float bj = b1[h];
        float mem[8], spk[8], ss[8], x1[8];
#pragma unroll
        for (int i = 0; i < 8; i++) {
            x1[i]  = acc[i][j] + bj;
            mem[i] = 0.f;
            ss[i]  = 0.f;
            spk[i] = (0.f > th) ? 1.f : 0.f;  // reset_0 = spike(-thr)
        }
#pragma unroll 1
        for (int t = 0; t < NSTEPS; t++) {
#pragma unroll
            for (int i = 0; i < 8; i++) {
                mem[i] = fmaf(spk[i], nth, fmaf(beta, mem[i], x1[i]));
                spk[i] = (mem[i] > th) ? 1.f : 0.f;
                ss[i] += spk[i];
            }
        }
#pragma unroll
        for (int i = 0; i < 8; i++) part[i] = fmaf(ss[i], w2, part[i]);
    }

    // ---- block reduction over 16 h-lane groups, one atomic per b ----
    __syncthreads();                          // all waves done reading GEMM LDS
    float (*red)[17] = (float (*)[17])smem;   // 128 x 17 floats, aliases xs
#pragma unroll
    for (int i = 0; i < 8; i++)
        red[wb_ + lty + 8 * i][ltx + 8 * (w & 1)] = part[i];
    __syncthreads();
    if (tid < BT) {
        float s = 0.f;
#pragma unroll
        for (int c = 0; c < 16; c++) s += red[tid][c];
        atomicAdd(&out[b0 + tid], s);
    }
}

extern "C" void kernel_launch(void* const* d_in, const int* in_sizes, int n_in,
                              void* d_out, int out_size, void* d_ws, size_t ws_size,
                              hipStream_t stream) {
    const float* x    = (const float*)d_in[0];
    const float* W1   = (const float*)d_in[1];
    const float* b1   = (const float*)d_in[2];
    const float* W2   = (const float*)d_in[3];
    const float* b2   = (const float*)d_in[4];
    const float* beta = (const float*)d_in[5];
    const float* thr  = (const float*)d_in[6];
    float* out = (float*)d_out;

    const int B = in_sizes[0] / NI;  // 32768

    snn_init<<<(B + 255) / 256, 256, 0, stream>>>(out, b2, B);

    dim3 grid(B / BT, NH / HT);
    snn_main<<<grid, 256, 0, stream>>>(x, W1, b1, W2, beta, thr, out);
}

// Round 5
// 210.500 us; speedup vs baseline: 2.5684x; 1.6895x over previous
//
#include <hip/hip_runtime.h>

// LeakySNN fused: out[b] = b2 + sum_h spksum(x1[b,h]) * W2[h]
// R5: GEMM moved to MFMA via fp16 two-term split (x=xh+xl, W=wh+wl;
//     x@W ~= xh@wh + xh@wl + xl@wh, error ~2^-22 -> x1 err ~1e-5).
//     fp32-VALU GEMM was stuck at ~165us (fma ~3cyc/wave effective, m07);
//     3 split-GEMMs on MFMA cost ~26us on an otherwise-idle pipe.
//     Scan trimmed to 4 VALU/step (select x1 vs x1-th, int spike counter).

#define NI 256
#define NH 1024
#define NSTEPS 25
#define BT 128
#define HT 128
#define BK 32
#define NTILES (NI / BK)
#define RW 40   // f16 per LDS row: 32 data + 8 pad = 80 B -> conflict-free frags

typedef _Float16 half8 __attribute__((ext_vector_type(8)));
typedef _Float16 half4 __attribute__((ext_vector_type(4)));
typedef float float4v __attribute__((ext_vector_type(4)));

__global__ __launch_bounds__(256) void snn_init(float* __restrict__ out,
                                                const float* __restrict__ b2, int B) {
    int i = blockIdx.x * 256 + threadIdx.x;
    if (i < B) out[i] = b2[0];
}

__global__ __launch_bounds__(256, 3) void snn_main(
    const float* __restrict__ x, const float* __restrict__ W1,
    const float* __restrict__ b1, const float* __restrict__ W2,
    const float* __restrict__ betap, const float* __restrict__ thr,
    float* __restrict__ out)
{
    __shared__ __align__(16) _Float16 lds[4 * BT * RW];  // 40 KB
    _Float16* xh = lds;
    _Float16* xl = lds + BT * RW;
    _Float16* wh = lds + 2 * BT * RW;
    _Float16* wl = lds + 3 * BT * RW;

    const int tid  = threadIdx.x;
    const int w    = tid >> 6;
    const int lane = tid & 63;
    const int col  = lane & 15;       // MFMA m/n lane
    const int quad = lane >> 4;       // MFMA k-group / C-row group
    const int wbb  = (w >> 1) * 64;   // wave b offset in tile
    const int whh  = (w & 1) * 64;    // wave h offset in tile
    const int b0 = blockIdx.x * BT;
    const int h0 = blockIdx.y * HT;

    float beta = betap[0];
    beta = beta < 0.f ? 0.f : (beta > 1.f ? 1.f : beta);

    float4v acc[4][4];
#pragma unroll
    for (int i = 0; i < 4; i++)
#pragma unroll
        for (int j = 0; j < 4; j++) acc[i][j] = (float4v){0.f, 0.f, 0.f, 0.f};

    // staging: float4 flat index f = tid + 256p -> row = tid/8 + 32p, col4 = tid&7
    const int r0 = tid >> 3;
    const int c4 = tid & 7;
    const float* xrow = x  + (size_t)(b0 + r0) * NI + 4 * c4;
    const float* wrow = W1 + (size_t)(h0 + r0) * NI + 4 * c4;

    for (int kt = 0; kt < NTILES; kt++) {
        const int ko = kt * BK;
        float4v vx[4], vw[4];
#pragma unroll
        for (int p = 0; p < 4; p++) {
            vx[p] = *(const float4v*)(xrow + (size_t)(32 * p) * NI + ko);
            vw[p] = *(const float4v*)(wrow + (size_t)(32 * p) * NI + ko);
        }
        __syncthreads();   // previous tile fully consumed
#pragma unroll
        for (int p = 0; p < 4; p++) {
            const int row = r0 + 32 * p;
            half4 hx, lx, hw, lw;
#pragma unroll
            for (int q = 0; q < 4; q++) {
                float v = vx[p][q];
                _Float16 h = (_Float16)v;          // RN to 11-bit mantissa
                hx[q] = h;
                lx[q] = (_Float16)(v - (float)h);  // Sterbenz-exact residual
                v = vw[p][q];
                h = (_Float16)v;
                hw[q] = h;
                lw[q] = (_Float16)(v - (float)h);
            }
            *(half4*)&xh[row * RW + 4 * c4] = hx;
            *(half4*)&xl[row * RW + 4 * c4] = lx;
            *(half4*)&wh[row * RW + 4 * c4] = hw;
            *(half4*)&wl[row * RW + 4 * c4] = lw;
        }
        __syncthreads();

        // fragments: A[m=col][k=quad*8+j], B[n=col][k=quad*8+j]
        half8 ah[4], al[4];
#pragma unroll
        for (int i = 0; i < 4; i++) {
            ah[i] = *(const half8*)&xh[(wbb + 16 * i + col) * RW + 8 * quad];
            al[i] = *(const half8*)&xl[(wbb + 16 * i + col) * RW + 8 * quad];
        }
#pragma unroll
        for (int j = 0; j < 4; j++) {
            half8 bh = *(const half8*)&wh[(whh + 16 * j + col) * RW + 8 * quad];
            half8 bl = *(const half8*)&wl[(whh + 16 * j + col) * RW + 8 * quad];
#pragma unroll
            for (int i = 0; i < 4; i++) {
                acc[i][j] = __builtin_amdgcn_mfma_f32_16x16x32_f16(ah[i], bh, acc[i][j], 0, 0, 0);
                acc[i][j] = __builtin_amdgcn_mfma_f32_16x16x32_f16(ah[i], bl, acc[i][j], 0, 0, 0);
                acc[i][j] = __builtin_amdgcn_mfma_f32_16x16x32_f16(al[i], bh, acc[i][j], 0, 0, 0);
            }
        }
    }

    // ---- LIF scan (reset_t == spk_{t-1}); 4 VALU/step, 8-wide ILP ----
    // C/D layout: b-row = wbb + 16i + 4*quad + r, h-col = whh + 16j + col.
    float part[16];
#pragma unroll
    for (int e = 0; e < 16; e++) part[e] = 0.f;

#pragma unroll
    for (int j = 0; j < 4; j++) {
        const int h = h0 + whh + 16 * j + col;
        const float th = thr[h];
        const float w2 = W2[h];
        const float bj = b1[h];
        const bool s0 = (0.f > th);    // reset_0 = spike(-thr)
#pragma unroll
        for (int half = 0; half < 2; half++) {   // 8-wide to cap VGPRs
            float x1[8], x1m[8], mem[8];
            int cnt[8];
            bool spk[8];
#pragma unroll
            for (int e = 0; e < 8; e++) {
                const int ee = e + 8 * half;
                x1[e]  = acc[ee >> 2][j][ee & 3] + bj;
                x1m[e] = x1[e] - th;
                mem[e] = 0.f; cnt[e] = 0; spk[e] = s0;
            }
#pragma unroll 1
            for (int t = 0; t < NSTEPS; t++) {
#pragma unroll
                for (int e = 0; e < 8; e++) {
                    mem[e] = fmaf(beta, mem[e], spk[e] ? x1m[e] : x1[e]);
                    spk[e] = mem[e] > th;
                    cnt[e] += spk[e];
                }
            }
#pragma unroll
            for (int e = 0; e < 8; e++)
                part[e + 8 * half] = fmaf((float)cnt[e], w2, part[e + 8 * half]);
        }
    }

    // ---- block reduction: red[128][33], then one atomic per b-row ----
    __syncthreads();                   // GEMM LDS dead; alias as red
    float* red = (float*)lds;
#pragma unroll
    for (int e = 0; e < 16; e++) {
        const int row = wbb + 16 * (e >> 2) + 4 * quad + (e & 3);
        red[row * 33 + (w & 1) * 16 + col] = part[e];
    }
    __syncthreads();
    if (tid < BT) {
        float s = 0.f;
#pragma unroll
        for (int c = 0; c < 32; c++) s += red[tid * 33 + c];
        atomicAdd(&out[b0 + tid], s);
    }
}

extern "C" void kernel_launch(void* const* d_in, const int* in_sizes, int n_in,
                              void* d_out, int out_size, void* d_ws, size_t ws_size,
                              hipStream_t stream) {
    const float* x    = (const float*)d_in[0];
    const float* W1   = (const float*)d_in[1];
    const float* b1   = (const float*)d_in[2];
    const float* W2   = (const float*)d_in[3];
    const float* b2   = (const float*)d_in[4];
    const float* beta = (const float*)d_in[5];
    const float* thr  = (const float*)d_in[6];
    float* out = (float*)d_out;

    const int B = in_sizes[0] / NI;  // 32768

    snn_init<<<(B + 255) / 256, 256, 0, stream>>>(out, b2, B);

    dim3 grid(B / BT, NH / HT);
    snn_main<<<grid, 256, 0, stream>>>(x, W1, b1, W2, beta, thr, out);
}

// Round 6
// 187.424 us; speedup vs baseline: 2.8847x; 1.1231x over previous
//
#include <hip/hip_runtime.h>

// LeakySNN fused: out[b] = b2 + sum_h spksum(x1[b,h]) * W2[h]
// R6: LIF scan replaced by breakpoint staircase. count(x1) over 25 steps is
//     monotone in x1 (LIF, subtractive reset, constant input), so
//     count(x1) = #{k : x1 >= c_k}; c_k (25 per h, 25600 total) bisected
//     exactly in ordered-float-bit space by a tiny kernel into d_ws.
//     Main-kernel scan: 50 VALU ops/elem (cmp+addc x25) vs 125 (sim).
//     GEMM stays fp16 two-term split on MFMA (R5).

#define NI 256
#define NH 1024
#define NSTEPS 25
#define BT 128
#define HT 128
#define BK 32
#define NTILES (NI / BK)
#define RW 40   // f16 per LDS row: 32 data + 8 pad = 80 B -> conflict-free frags

typedef _Float16 half8 __attribute__((ext_vector_type(8)));
typedef _Float16 half4 __attribute__((ext_vector_type(4)));
typedef float float4v __attribute__((ext_vector_type(4)));

__device__ __forceinline__ unsigned f2k(float f) {
    unsigned u = __float_as_uint(f);
    return (u >> 31) ? ~u : (u | 0x80000000u);
}
__device__ __forceinline__ float k2f(unsigned k) {
    unsigned u = (k & 0x80000000u) ? (k & 0x7FFFFFFFu) : ~k;
    return __uint_as_float(u);
}

// 25-step LIF spike count, R4 arithmetic (closest match to reference,
// absmax 0.0156): reset_t == spk_{t-1}, reset_0 = spike(-thr).
__device__ __forceinline__ int lif_count(float x1, float beta, float th) {
    float mem = 0.f;
    float spk = (0.f > th) ? 1.f : 0.f;
    int c = 0;
#pragma unroll
    for (int t = 0; t < NSTEPS; t++) {
        mem = fmaf(spk, -th, fmaf(beta, mem, x1));
        spk = (mem > th) ? 1.f : 0.f;
        c += (mem > th);
    }
    return c;
}

__global__ __launch_bounds__(256) void snn_init(float* __restrict__ out,
                                                const float* __restrict__ b2, int B) {
    int i = blockIdx.x * 256 + threadIdx.x;
    if (i < B) out[i] = b2[0];
}

// One thread per (h, k): c_k[h] = smallest float x1 with count >= k.
// Stored k-major: bp[k*NH + h] (coalesced loads in main kernel).
__global__ __launch_bounds__(256) void snn_bp(
    const float* __restrict__ thr, const float* __restrict__ betap,
    float* __restrict__ bp)
{
    int idx = blockIdx.x * 256 + threadIdx.x;
    if (idx >= NH * NSTEPS) return;
    const int h = idx / NSTEPS;
    const int k = idx % NSTEPS + 1;   // target count 1..25
    const float th = thr[h];
    float beta = betap[0];
    beta = beta < 0.f ? 0.f : (beta > 1.f ? 1.f : beta);

    unsigned lo = f2k(-3.0e38f), hi = f2k(3.0e38f);
    float res;
    if (lif_count(k2f(hi), beta, th) < k) {
        res = 3.0e38f;                 // never fires k times: x1 >= c never true
    } else if (lif_count(k2f(lo), beta, th) >= k) {
        res = -3.0e38f;                // always fires k times
    } else {
#pragma unroll 1
        for (int it = 0; it < 32; it++) {
            unsigned mid = lo + ((hi - lo) >> 1);
            if (lif_count(k2f(mid), beta, th) >= k) hi = mid; else lo = mid;
        }
        res = k2f(hi);
    }
    bp[(k - 1) * NH + h] = res;
}

__global__ __launch_bounds__(256, 3) void snn_main(
    const float* __restrict__ x, const float* __restrict__ W1,
    const float* __restrict__ b1, const float* __restrict__ W2,
    const float* __restrict__ bp, const float* __restrict__ thr,
    float* __restrict__ out)
{
    __shared__ __align__(16) _Float16 lds[4 * BT * RW];  // 40 KB
    _Float16* xh = lds;
    _Float16* xl = lds + BT * RW;
    _Float16* wh = lds + 2 * BT * RW;
    _Float16* wl = lds + 3 * BT * RW;

    const int tid  = threadIdx.x;
    const int w    = tid >> 6;
    const int lane = tid & 63;
    const int col  = lane & 15;       // MFMA m/n lane
    const int quad = lane >> 4;       // MFMA k-group / C-row group
    const int wbb  = (w >> 1) * 64;   // wave b offset in tile
    const int whh  = (w & 1) * 64;    // wave h offset in tile
    const int b0 = blockIdx.x * BT;
    const int h0 = blockIdx.y * HT;

    float4v acc[4][4];
#pragma unroll
    for (int i = 0; i < 4; i++)
#pragma unroll
        for (int j = 0; j < 4; j++) acc[i][j] = (float4v){0.f, 0.f, 0.f, 0.f};

    // staging: float4 flat index f = tid + 256p -> row = tid/8 + 32p, col4 = tid&7
    const int r0 = tid >> 3;
    const int c4 = tid & 7;
    const float* xrow = x  + (size_t)(b0 + r0) * NI + 4 * c4;
    const float* wrow = W1 + (size_t)(h0 + r0) * NI + 4 * c4;

    for (int kt = 0; kt < NTILES; kt++) {
        const int ko = kt * BK;
        float4v vx[4], vw[4];
#pragma unroll
        for (int p = 0; p < 4; p++) {
            vx[p] = *(const float4v*)(xrow + (size_t)(32 * p) * NI + ko);
            vw[p] = *(const float4v*)(wrow + (size_t)(32 * p) * NI + ko);
        }
        __syncthreads();   // previous tile fully consumed
#pragma unroll
        for (int p = 0; p < 4; p++) {
            const int row = r0 + 32 * p;
            half4 hx, lx, hw, lw;
#pragma unroll
            for (int q = 0; q < 4; q++) {
                float v = vx[p][q];
                _Float16 h = (_Float16)v;          // RN to 11-bit mantissa
                hx[q] = h;
                lx[q] = (_Float16)(v - (float)h);  // Sterbenz-exact residual
                v = vw[p][q];
                h = (_Float16)v;
                hw[q] = h;
                lw[q] = (_Float16)(v - (float)h);
            }
            *(half4*)&xh[row * RW + 4 * c4] = hx;
            *(half4*)&xl[row * RW + 4 * c4] = lx;
            *(half4*)&wh[row * RW + 4 * c4] = hw;
            *(half4*)&wl[row * RW + 4 * c4] = lw;
        }
        __syncthreads();

        // fragments: A[m=col][k=quad*8+j], B[n=col][k=quad*8+j]
        half8 ah[4], al[4];
#pragma unroll
        for (int i = 0; i < 4; i++) {
            ah[i] = *(const half8*)&xh[(wbb + 16 * i + col) * RW + 8 * quad];
            al[i] = *(const half8*)&xl[(wbb + 16 * i + col) * RW + 8 * quad];
        }
#pragma unroll
        for (int j = 0; j < 4; j++) {
            half8 bh = *(const half8*)&wh[(whh + 16 * j + col) * RW + 8 * quad];
            half8 bl = *(const half8*)&wl[(whh + 16 * j + col) * RW + 8 * quad];
#pragma unroll
            for (int i = 0; i < 4; i++) {
                acc[i][j] = __builtin_amdgcn_mfma_f32_16x16x32_f16(ah[i], bh, acc[i][j], 0, 0, 0);
                acc[i][j] = __builtin_amdgcn_mfma_f32_16x16x32_f16(ah[i], bl, acc[i][j], 0, 0, 0);
                acc[i][j] = __builtin_amdgcn_mfma_f32_16x16x32_f16(al[i], bh, acc[i][j], 0, 0, 0);
            }
        }
    }

    // ---- stage this h-tile's breakpoints: bpl[k][128], conflict-free reads ----
    __syncthreads();                   // GEMM LDS dead
    float* bpl = (float*)lds;          // 25*128 floats = 12.8 KB
    for (int n = tid; n < NSTEPS * 128; n += 256)
        bpl[n] = bp[(n >> 7) * NH + h0 + (n & 127)];
    __syncthreads();

    // ---- staircase count: cnt = #{k : x1 >= c_k};  2 VALU per (elem,k) ----
    // C/D layout: b-row = wbb + 16i + 4*quad + r, h-col = whh + 16j + col.
    float part[16];
#pragma unroll
    for (int e = 0; e < 16; e++) part[e] = 0.f;

#pragma unroll
    for (int j = 0; j < 4; j++) {
        const int hl = whh + 16 * j + col;   // local h in tile
        const int h = h0 + hl;
        const float w2 = W2[h];
        const float bj = b1[h];
        float x1[16];
        int cnt[16];
#pragma unroll
        for (int e = 0; e < 16; e++) {
            x1[e] = acc[e >> 2][j][e & 3] + bj;
            cnt[e] = 0;
        }
#pragma unroll
        for (int k = 0; k < NSTEPS; k++) {
            const float c = bpl[k * 128 + hl];   // 16 banks x 4-way bcast: free
#pragma unroll
            for (int e = 0; e < 16; e++) cnt[e] += (x1[e] >= c) ? 1 : 0;
        }
#pragma unroll
        for (int e = 0; e < 16; e++)
            part[e] = fmaf((float)cnt[e], w2, part[e]);
    }

    // ---- block reduction: red[128][33], then one atomic per b-row ----
    __syncthreads();                   // bpl dead; alias as red
    float* red = (float*)lds;
#pragma unroll
    for (int e = 0; e < 16; e++) {
        const int row = wbb + 16 * (e >> 2) + 4 * quad + (e & 3);
        red[row * 33 + (w & 1) * 16 + col] = part[e];
    }
    __syncthreads();
    if (tid < BT) {
        float s = 0.f;
#pragma unroll
        for (int c = 0; c < 32; c++) s += red[tid * 33 + c];
        atomicAdd(&out[b0 + tid], s);
    }
}

extern "C" void kernel_launch(void* const* d_in, const int* in_sizes, int n_in,
                              void* d_out, int out_size, void* d_ws, size_t ws_size,
                              hipStream_t stream) {
    const float* x    = (const float*)d_in[0];
    const float* W1   = (const float*)d_in[1];
    const float* b1   = (const float*)d_in[2];
    const float* W2   = (const float*)d_in[3];
    const float* b2   = (const float*)d_in[4];
    const float* beta = (const float*)d_in[5];
    const float* thr  = (const float*)d_in[6];
    float* out = (float*)d_out;
    float* bp  = (float*)d_ws;         // NH*NSTEPS floats = 102 KB

    const int B = in_sizes[0] / NI;  // 32768

    snn_init<<<(B + 255) / 256, 256, 0, stream>>>(out, b2, B);
    snn_bp<<<(NH * NSTEPS + 255) / 256, 256, 0, stream>>>(thr, beta, bp);

    dim3 grid(B / BT, NH / HT);
    snn_main<<<grid, 256, 0, stream>>>(x, W1, b1, W2, bp, thr, out);
}